// Round 1
// 1106.424 us; speedup vs baseline: 1.0940x; 1.0940x over previous
//
#include <hip/hip_runtime.h>
#include <hip/hip_bf16.h>
#include <math.h>

// FFTConvNet: out = relu(Re(ifft2( (fft2(x) per-freq complex-contract W) )) + bias)
// B=32, CIN=COUT=64, H=W=128.
// Pipeline:
//   k_fft_rows      : x fp32 -> row-FFT (wave-shuffle, no LDS) -> XF bf16 complex
//   k_fft_cols(-1)  : column FFT in-place on XF (LDS tile)
//   k_cgemm         : per-freq complex contraction, global_load_lds + double-buffer
//                     (v2: 64-wide o-tile -> XF + W each fetched from HBM exactly once)
//   k_fft_cols(+1)  : column IFFT in-place on Y
//   k_ifft_rows_out : row IFFT (wave-shuffle) + 1/16384 + bias + relu -> out fp32

#define PI2 6.28318530717958647692f
typedef unsigned int uint32;

__device__ __forceinline__ float2 cmulf(float2 a, float2 b) {
  return make_float2(a.x * b.x - a.y * b.y, a.x * b.y + a.y * b.x);
}
__device__ __forceinline__ uint32 pack_bf(float re, float im) {
  __hip_bfloat162 h;
  h.x = __float2bfloat16(re);
  h.y = __float2bfloat16(im);
  return *(uint32*)&h;
}
__device__ __forceinline__ float2 unpack_bf(uint32 v) {
  return make_float2(__uint_as_float(v << 16), __uint_as_float(v & 0xFFFF0000u));
}
__device__ __forceinline__ int br7(int i) { return __brev((unsigned)i) >> 25; }

// ---------- In-wave 128-pt DIT FFT: lane l holds a = l and a = l+64 ----------
// Input must be loaded bit-reversed: e0 = in[br7(l)], e1 = in[br7(l)+1].
// Output is natural order: e0 -> bin l, e1 -> bin l+64. sign=-1 fwd, +1 inv.
template <int SGN>
__device__ __forceinline__ void wave_fft128(float2& e0, float2& e1, int l) {
#pragma unroll
  for (int s = 1; s <= 6; s++) {
    const int h = 1 << (s - 1);
    const int p = l & (h - 1);
    float sn, cs;
    __sincosf((float)SGN * PI2 * (float)p / (float)(2 * h), &sn, &cs);
    const float2 w = make_float2(cs, sn);
    const bool up = (l & h) != 0;
    const float2 o0 = make_float2(__shfl_xor(e0.x, h), __shfl_xor(e0.y, h));
    const float2 o1 = make_float2(__shfl_xor(e1.x, h), __shfl_xor(e1.y, h));
    const float2 u0 = up ? o0 : e0;
    const float2 m0 = up ? e0 : o0;
    const float2 u1 = up ? o1 : e1;
    const float2 m1 = up ? e1 : o1;
    const float2 t0 = cmulf(w, m0);
    const float2 t1 = cmulf(w, m1);
    e0 = up ? make_float2(u0.x - t0.x, u0.y - t0.y) : make_float2(u0.x + t0.x, u0.y + t0.y);
    e1 = up ? make_float2(u1.x - t1.x, u1.y - t1.y) : make_float2(u1.x + t1.x, u1.y + t1.y);
  }
  // stage 7: pair (l, l+64) in-register, twiddle W128^l
  float sn, cs;
  __sincosf((float)SGN * PI2 * (float)l * (1.0f / 128.0f), &sn, &cs);
  const float2 w = make_float2(cs, sn);
  const float2 t = cmulf(w, e1);
  const float2 u = e0;
  e0 = make_float2(u.x + t.x, u.y + t.y);
  e1 = make_float2(u.x - t.x, u.y - t.y);
}

// ---------------- Pass 1a: forward row FFTs (fp32 real in, bf16 complex out) ----------------
__global__ __launch_bounds__(256) void k_fft_rows(const float* __restrict__ x,
                                                  uint32* __restrict__ xf) {
  const int t = threadIdx.x, l = t & 63, wv = t >> 6;
  const int row = blockIdx.x * 4 + wv;
  const float* rp = x + (size_t)row * 128;
  const int brl = br7(l);  // even; br7(l+64) = brl+1
  const float2 v = *(const float2*)(rp + brl);
  float2 e0 = make_float2(v.x, 0.f);
  float2 e1 = make_float2(v.y, 0.f);
  wave_fft128<-1>(e0, e1, l);
  uint32* op = xf + (size_t)row * 128;
  op[l] = pack_bf(e0.x, e0.y);
  op[l + 64] = pack_bf(e1.x, e1.y);
}

// ---------------- Pass 1b / 3a: column FFT/IFFT, in-place, bf16 complex ----------------
__global__ __launch_bounds__(256) void k_fft_cols(uint32* __restrict__ buf, float sign) {
  __shared__ float2 tw[64];
  __shared__ float2 tile[128][33];
  const int t = threadIdx.x;
  if (t < 64) {
    float s, c;
    sincosf(sign * PI2 * (float)t * (1.0f / 128.0f), &s, &c);
    tw[t] = make_float2(c, s);
  }
  const int img = blockIdx.x >> 2;
  const int w0 = (blockIdx.x & 3) * 32;
  uint32* base = buf + img * 16384 + w0;
  const int j = t & 31, hh = t >> 5;
#pragma unroll
  for (int it = 0; it < 16; it++) {
    const int h = it * 8 + hh;
    tile[br7(h)][j] = unpack_bf(base[h * 128 + j]);
  }
  __syncthreads();
#pragma unroll
  for (int s = 0; s < 7; s++) {
    const int half = 1 << s;
#pragma unroll
    for (int kk = 0; kk < 8; kk++) {
      const int k = kk * 8 + hh;
      const int p = k & (half - 1);
      const int i0 = ((k >> s) << (s + 1)) + p;
      const int i1 = i0 + half;
      const float2 w = tw[p << (6 - s)];
      const float2 u = tile[i0][j];
      const float2 v = tile[i1][j];
      const float2 wv = cmulf(w, v);
      tile[i0][j] = make_float2(u.x + wv.x, u.y + wv.y);
      tile[i1][j] = make_float2(u.x - wv.x, u.y - wv.y);
    }
    __syncthreads();
  }
#pragma unroll
  for (int it = 0; it < 16; it++) {
    const int h = it * 8 + hh;
    base[h * 128 + j] = pack_bf(tile[h][j].x, tile[h][j].y);
  }
}

// ---------------- Pass 2: per-frequency complex contraction ----------------
// v2: block = 16 freqs x ALL 64 o x ALL 32 b, 512 threads. Every weight element
// and every XF element is fetched from HBM exactly once (fetch 1.074 GB -> 671 MB).
// Lane map: fl=t&15 (freq), grp=t>>4 (0..31) -> o pair {2*grp, 2*grp+1}; each
// thread accumulates 32b x 2o complex = 128 VGPRs.
// XF: async global_load_lds dwordx4 into double-buffered LDS, staged one c-chunk
// (8 c's, 16 KB) ahead; LDS reads are 16-address broadcasts (conflict-free).
// Weights: per-thread scalar fp32 loads, software-pipelined one c ahead.
__global__ __launch_bounds__(512, 2) void k_cgemm(const uint32* __restrict__ xf,
                                                  const float* __restrict__ wr,
                                                  const float* __restrict__ wi,
                                                  uint32* __restrict__ y) {
  __shared__ uint32 xs[2][4096];  // [buf][(cc*32+b)*16 + f]
  const int t = threadIdx.x;
  const int f0 = blockIdx.x * 16;  // 1024 blocks over freq
  const int fl = t & 15;
  const int grp = t >> 4;  // 0..31
  const int o0 = grp * 2;
  const int wv = t >> 6;  // wave id 0..7

  float2 acc[32][2] = {};  // [b][jo]

  auto stage = [&](int ci, int d) {
    // 1024 lane-chunks of 16B: s = q*512 + t; r = s>>2 = cc*32+b; fq = s&3.
#pragma unroll
    for (int q = 0; q < 2; q++) {
      const int s = q * 512 + t;
      const int r = s >> 2, fq = s & 3;
      const int cc = r >> 5, b = r & 31;
      const uint32* gp = xf + (size_t)(b * 64 + ci * 8 + cc) * 16384u +
                         (unsigned)(f0 + fq * 4);
      uint32* lp = &xs[d][(unsigned)(q * 512 + wv * 64) * 4u];  // wave-uniform base
      __builtin_amdgcn_global_load_lds(
          (const __attribute__((address_space(1))) unsigned int*)gp,
          (__attribute__((address_space(3))) unsigned int*)lp, 16, 0, 0);
    }
  };

  const float* wrp = wr + (size_t)o0 * 64 * 16384 + (unsigned)(f0 + fl);
  const float* wip = wi + (size_t)o0 * 64 * 16384 + (unsigned)(f0 + fl);

  stage(0, 0);
  // software-pipelined weight registers (current c in a*, next c loading)
  float w0r = wrp[0], w1r = wrp[(size_t)64 * 16384];
  float w0i = wip[0], w1i = wip[(size_t)64 * 16384];

  for (int ci = 0; ci < 8; ci++) {
    __syncthreads();  // drains this chunk's async loads (vmcnt0 before barrier)
    if (ci < 7) stage(ci + 1, (ci + 1) & 1);  // prefetch next chunk, other buffer
    const int d = ci & 1;
#pragma unroll 2
    for (int cc = 0; cc < 8; cc++) {
      const int c = ci * 8 + cc;
      const float a0r = w0r, a1r = w1r, a0i = w0i, a1i = w1i;
      const int cn = (c < 63) ? c + 1 : 63;  // clamped prefetch of next c
      w0r = wrp[(size_t)cn * 16384];
      w1r = wrp[(size_t)(64 + cn) * 16384];
      w0i = wip[(size_t)cn * 16384];
      w1i = wip[(size_t)(64 + cn) * 16384];
#pragma unroll
      for (int b = 0; b < 32; b++) {
        const float2 xv = unpack_bf(xs[d][(cc * 32 + b) * 16 + fl]);
        acc[b][0].x = fmaf(xv.x, a0r, acc[b][0].x);
        acc[b][0].x = fmaf(-xv.y, a0i, acc[b][0].x);
        acc[b][0].y = fmaf(xv.x, a0i, acc[b][0].y);
        acc[b][0].y = fmaf(xv.y, a0r, acc[b][0].y);
        acc[b][1].x = fmaf(xv.x, a1r, acc[b][1].x);
        acc[b][1].x = fmaf(-xv.y, a1i, acc[b][1].x);
        acc[b][1].y = fmaf(xv.x, a1i, acc[b][1].y);
        acc[b][1].y = fmaf(xv.y, a1r, acc[b][1].y);
      }
    }
  }
#pragma unroll
  for (int b = 0; b < 32; b++) {
    y[(size_t)(b * 64 + o0) * 16384u + (unsigned)(f0 + fl)] =
        pack_bf(acc[b][0].x, acc[b][0].y);
    y[(size_t)(b * 64 + o0 + 1) * 16384u + (unsigned)(f0 + fl)] =
        pack_bf(acc[b][1].x, acc[b][1].y);
  }
}

// ---------------- Pass 3b: inverse row FFTs + scale + bias + relu ----------------
__global__ __launch_bounds__(256) void k_ifft_rows_out(const uint32* __restrict__ y,
                                                       const float* __restrict__ bias,
                                                       float* __restrict__ out) {
  const int t = threadIdx.x, l = t & 63, wv = t >> 6;
  const int row = blockIdx.x * 4 + wv;  // (b*64+o)*128 + h
  const uint32* rp = y + (size_t)row * 128;
  const int brl = br7(l);
  const uint2 u = *(const uint2*)(rp + brl);
  float2 e0 = unpack_bf(u.x);
  float2 e1 = unpack_bf(u.y);
  wave_fft128<1>(e0, e1, l);
  const int o = (row >> 7) & 63;
  const float bb = bias[o];
  const float sc = 1.0f / 16384.0f;
  float* op = out + (size_t)row * 128;
  op[l] = fmaxf(fmaf(e0.x, sc, bb), 0.f);
  op[l + 64] = fmaxf(fmaf(e1.x, sc, bb), 0.f);
}

extern "C" void kernel_launch(void* const* d_in, const int* in_sizes, int n_in,
                              void* d_out, int out_size, void* d_ws, size_t ws_size,
                              hipStream_t stream) {
  const float* x = (const float*)d_in[0];
  const float* wr = (const float*)d_in[1];
  const float* wi = (const float*)d_in[2];
  const float* bias = (const float*)d_in[3];
  float* out = (float*)d_out;

  const size_t XF_BYTES = 134217728;  // 2048 * 16384 * 4B (bf16 complex)
  if (ws_size < 2 * XF_BYTES) {
    hipMemsetAsync(d_out, 0, (size_t)out_size * sizeof(float), stream);
    return;
  }
  uint32* XF = (uint32*)d_ws;
  uint32* Y = (uint32*)((char*)d_ws + XF_BYTES);

  k_fft_rows<<<65536, 256, 0, stream>>>(x, XF);
  k_fft_cols<<<8192, 256, 0, stream>>>(XF, -1.0f);
  k_cgemm<<<1024, 512, 0, stream>>>(XF, wr, wi, Y);
  k_fft_cols<<<8192, 256, 0, stream>>>(Y, 1.0f);
  k_ifft_rows_out<<<65536, 256, 0, stream>>>(Y, bias, out);
}